// Round 6
// baseline (361.987 us; speedup 1.0000x reference)
//
#include <hip/hip_runtime.h>
#include <math.h>

#define T_OBS 256
#define NY 128
#define NITER 150

typedef float f2   __attribute__((ext_vector_type(2)));
typedef float f16v __attribute__((ext_vector_type(16)));

// ---- gfx9/CDNA DPP wave64 reduction: row_shr 1,2,4,8 + bcast15 + bcast31 ----
#define DPP_ROW_SHR1 0x111
#define DPP_ROW_SHR2 0x112
#define DPP_ROW_SHR4 0x114
#define DPP_ROW_SHR8 0x118
#define DPP_BCAST15  0x142
#define DPP_BCAST31  0x143

#define DPP_ADD_F32(x, ctrl) \
    (x) += __int_as_float(__builtin_amdgcn_update_dpp(0, __float_as_int(x), (ctrl), 0xf, 0xf, true))

// Interleaved dual wave-sum; returns uniform totals in a,b.
__device__ __forceinline__ void wave_sum2(float& a, float& b) {
    DPP_ADD_F32(a, DPP_ROW_SHR1); DPP_ADD_F32(b, DPP_ROW_SHR1);
    DPP_ADD_F32(a, DPP_ROW_SHR2); DPP_ADD_F32(b, DPP_ROW_SHR2);
    DPP_ADD_F32(a, DPP_ROW_SHR4); DPP_ADD_F32(b, DPP_ROW_SHR4);
    DPP_ADD_F32(a, DPP_ROW_SHR8); DPP_ADD_F32(b, DPP_ROW_SHR8);
    DPP_ADD_F32(a, DPP_BCAST15);  DPP_ADD_F32(b, DPP_BCAST15);
    DPP_ADD_F32(a, DPP_BCAST31);  DPP_ADD_F32(b, DPP_BCAST31);
    a = __int_as_float(__builtin_amdgcn_readlane(__float_as_int(a), 63));
    b = __int_as_float(__builtin_amdgcn_readlane(__float_as_int(b), 63));
}

__device__ __forceinline__ float rl(float x, int l) {
    return __int_as_float(__builtin_amdgcn_readlane(__float_as_int(x), l));
}

// ---------------- kernel 1: Y_hat = X @ W^T + b ; ep = Y - Y_hat ----------------
__global__ __launch_bounds__(128)
void pred_kernel(const float* __restrict__ X, const float* __restrict__ Y,
                 const float* __restrict__ W, const float* __restrict__ b,
                 float* __restrict__ yhat, float* __restrict__ ep) {
    __shared__ float xrow[64];
    const int t = blockIdx.x;
    const int j = threadIdx.x;
    if (j < 64) xrow[j] = X[t * 64 + j];
    __syncthreads();
    const float* wr = W + j * 64;
    float acc = 0.f;
#pragma unroll
    for (int x = 0; x < 64; ++x) acc = fmaf(xrow[x], wr[x], acc);
    const float yh = acc + b[j];
    yhat[t * NY + j] = yh;
    ep[t * NY + j] = Y[t * NY + j] - yh;
}

// ---- phase A step: 4 columns (4qi..4qi+3) of this thread's row ----
#define A_STEP(V, s, qi) {                      \
    const float za = rl(z0, 2 * (qi));          \
    const float zb = rl(z1, 2 * (qi));          \
    const float zc = rl(z0, 2 * (qi) + 1);      \
    const float zd = rl(z1, 2 * (qi) + 1);      \
    a0 = fmaf((V)[(s) + 0], za, a0);            \
    a1 = fmaf((V)[(s) + 1], zb, a1);            \
    a2 = fmaf((V)[(s) + 2], zc, a2);            \
    a3 = fmaf((V)[(s) + 3], zd, a3); }
#define A_VEC(V, qb) \
    A_STEP(V, 0, qb) A_STEP(V, 4, (qb) + 1) A_STEP(V, 8, (qb) + 2) A_STEP(V, 12, (qb) + 3)

// ---- phase B step: rows ti, ti+1 (this lane's 2 columns) ----
#define B_STEP(V, s, ti) {                      \
    const float wa = rl(wv, (ti));              \
    const float wb = rl(wv, (ti) + 1);          \
    p0 = fmaf(wa, (V)[(s) + 0], p0);            \
    p1 = fmaf(wa, (V)[(s) + 1], p1);            \
    p2 = fmaf(wb, (V)[(s) + 2], p2);            \
    p3 = fmaf(wb, (V)[(s) + 3], p3); }
#define B_VEC(V, tb) \
    B_STEP(V, 0, tb) B_STEP(V, 4, (tb) + 2) B_STEP(V, 8, (tb) + 4) B_STEP(V, 12, (tb) + 6)

// ---- load 8 rows (rb..rb+7) x 2 cols into one 16-wide vector ----
#define LOAD_B(V, rb) {                                                   \
    const f2 e0 = *(const f2*)(ep_g + (tbase + (rb) + 0) * NY + j0);      \
    const f2 e1 = *(const f2*)(ep_g + (tbase + (rb) + 1) * NY + j0);      \
    const f2 e2 = *(const f2*)(ep_g + (tbase + (rb) + 2) * NY + j0);      \
    const f2 e3 = *(const f2*)(ep_g + (tbase + (rb) + 3) * NY + j0);      \
    const f2 e4 = *(const f2*)(ep_g + (tbase + (rb) + 4) * NY + j0);      \
    const f2 e5 = *(const f2*)(ep_g + (tbase + (rb) + 5) * NY + j0);      \
    const f2 e6 = *(const f2*)(ep_g + (tbase + (rb) + 6) * NY + j0);      \
    const f2 e7 = *(const f2*)(ep_g + (tbase + (rb) + 7) * NY + j0);      \
    V = (f16v){e0.x, e0.y, e1.x, e1.y, e2.x, e2.y, e3.x, e3.y,            \
               e4.x, e4.y, e5.x, e5.y, e6.x, e6.y, e7.x, e7.y}; }

// ---------------- kernel 2: one DRO solve per block ----------------
// R1 structure (readlane broadcasts, ONE barrier/iter). ep tiles live in
// NAMED 16-wide vector registers with an in-loop empty-asm keepalive:
// each iteration redefines them through opaque asm, so the register
// allocator cannot rematerialize the tile loads inside the k-loop
// (R1/R3 showed VGPR_Count=152 < 256 tile regs => per-iter reloads).
__global__ __launch_bounds__(256, 1)
void dro_kernel(const float* __restrict__ ep_g, const float* __restrict__ yhat_g,
                float* __restrict__ z_out,
                const float* __restrict__ d_delta, const float* __restrict__ d_gamma) {
    __shared__ float gzp[2][4][NY];              // cross-wave partials, dbuf
    __shared__ __align__(16) float red[2][8];    // cross-wave {S1,S2}, dbuf

    const int tid  = threadIdx.x;
    const int lane = tid & 63;
    const int wid  = tid >> 6;
    const int blk  = blockIdx.x;
    const int j0    = lane << 1;
    const int tbase = wid << 6;

    // row layout: thread tid holds ep[tid][0..127] in A0..A7 (128 VGPRs)
    const float* abase = ep_g + tid * NY;
    f16v A0 = *(const f16v*)(abase +   0);
    f16v A1 = *(const f16v*)(abase +  16);
    f16v A2 = *(const f16v*)(abase +  32);
    f16v A3 = *(const f16v*)(abase +  48);
    f16v A4 = *(const f16v*)(abase +  64);
    f16v A5 = *(const f16v*)(abase +  80);
    f16v A6 = *(const f16v*)(abase +  96);
    f16v A7 = *(const f16v*)(abase + 112);

    // col layout: lane holds ep[tbase+tt][j0..j0+1] in B0..B7 (128 VGPRs)
    f16v B0, B1, B2, B3, B4, B5, B6, B7;
    LOAD_B(B0,  0) LOAD_B(B1,  8) LOAD_B(B2, 16) LOAD_B(B3, 24)
    LOAD_B(B4, 32) LOAD_B(B5, 40) LOAD_B(B6, 48) LOAD_B(B7, 56)

    const float yh0 = yhat_g[blk * NY + j0];
    const float yh1 = yhat_g[blk * NY + j0 + 1];

    // z pair in registers (each wave holds a full redundant copy across lanes)
    float z0 = 1.0f / 128.0f, z1 = 1.0f / 128.0f;
    // Michelot warm-start support indicators (carried across iterations)
    float act0 = 1.f, act1 = 1.f;

    const float delta = d_delta[0];
    const float gamma = d_gamma[0];
    float c = 0.f, eta = 0.f, lam = 0.1f;
    int buf = 0;

    for (int k = 0; k < NITER; ++k) {
        // keepalive: redefine the tile registers through opaque asm each
        // iteration -> values are loop-carried, remat from global is illegal.
        asm volatile("" : "+v"(A0), "+v"(A1), "+v"(A2), "+v"(A3),
                          "+v"(A4), "+v"(A5), "+v"(A6), "+v"(A7));
        asm volatile("" : "+v"(B0), "+v"(B1), "+v"(B2), "+v"(B3),
                          "+v"(B4), "+v"(B5), "+v"(B6), "+v"(B7));

        const float lr = 0.05f * __builtin_amdgcn_rsqf(1.0f + (float)k);

        // ---- phase A: r_t = ep[t,:].z - c ; z broadcast via readlane ----
        float a0 = 0.f, a1 = 0.f, a2 = 0.f, a3 = 0.f;
        A_VEC(A0,  0) A_VEC(A1,  4) A_VEC(A2,  8) A_VEC(A3, 12)
        A_VEC(A4, 16) A_VEC(A5, 20) A_VEC(A6, 24) A_VEC(A7, 28)
        const float r  = (a0 + a1) + (a2 + a3) - c;
        const float q2 = r * r - eta;
        const float aa = -lam;
        const float st = (q2 > aa) ? 1.0f : ((q2 == aa) ? 0.5f : 0.0f);
        const float wv = st * r;

        // ---- S1/S2 reduction (independent of phase B; scheduler interleaves) ----
        float s1 = st, s2 = wv;
        wave_sum2(s1, s2);
        if (lane == 0) { red[buf][wid * 2] = s1; red[buf][wid * 2 + 1] = s2; }

        // ---- phase B: per-wave partial gz over own 64 rows; w via readlane ----
        float p0 = 0.f, p1 = 0.f, p2 = 0.f, p3 = 0.f;
        B_VEC(B0,  0) B_VEC(B1,  8) B_VEC(B2, 16) B_VEC(B3, 24)
        B_VEC(B4, 32) B_VEC(B5, 40) B_VEC(B6, 48) B_VEC(B7, 56)
        *(float2*)&gzp[buf][wid][j0] = make_float2(p0 + p2, p1 + p3);

        __syncthreads();   // the ONE barrier: gzp[buf] + red[buf] visible

        // ---- all waves redundantly: scalar updates + z step + projection ----
        const float4 rd0 = *(const float4*)&red[buf][0];
        const float4 rd1 = *(const float4*)&red[buf][4];
        const float S1 = (rd0.x + rd0.z) + (rd1.x + rd1.z);
        const float S2 = (rd0.y + rd0.w) + (rd1.y + rd1.w);
        c   -= lr * (-(2.0f / 256.0f) * S2);
        eta -= lr * (1.0f - S1 * (1.0f / 256.0f));
        lam  = fmaxf(lam - lr * (delta - 1.0f + S1 * (1.0f / 256.0f)), 0.0f);

        const float2 g0v = *(const float2*)&gzp[buf][0][j0];
        const float2 g1v = *(const float2*)&gzp[buf][1][j0];
        const float2 g2v = *(const float2*)&gzp[buf][2][j0];
        const float2 g3v = *(const float2*)&gzp[buf][3][j0];
        const float g0 = (g0v.x + g1v.x) + (g2v.x + g3v.x);
        const float g1 = (g0v.y + g1v.y) + (g2v.y + g3v.y);
        const float v0 = z0 - lr * ((2.0f / 256.0f) * g0 - gamma * yh0);
        const float v1 = z1 - lr * ((2.0f / 256.0f) * g1 - gamma * yh1);

        // ---- Michelot projection: warm start + ballot fixed-point test.
        // Fixed point + no external violator == exact KKT theta.
        float theta = 0.f;
        for (int attempt = 0; attempt < 2; ++attempt) {
            for (int m = 0; m < 128; ++m) {
                float s  = act0 * v0 + act1 * v1;
                float cc = act0 + act1;
                wave_sum2(s, cc);
                theta = (s - 1.0f) * __builtin_amdgcn_rcpf(cc);
                const float n0 = (v0 > theta) ? act0 : 0.f;
                const float n1 = (v1 > theta) ? act1 : 0.f;
                const bool changed = (n0 != act0) || (n1 != act1);
                act0 = n0; act1 = n1;
                if (!__any(changed)) break;   // uniform
            }
            const bool viol = ((act0 == 0.f) && (v0 > theta)) ||
                              ((act1 == 0.f) && (v1 > theta));
            if (!__any(viol)) break;          // exact
            act0 = 1.f; act1 = 1.f;           // rare: support grew, restart full
        }
        z0 = fmaxf(v0 - theta, 0.f);
        z1 = fmaxf(v1 - theta, 0.f);

        buf ^= 1;
    }

    if (wid == 0) *(float2*)&z_out[blk * NY + j0] = make_float2(z0, z1);
}

extern "C" void kernel_launch(void* const* d_in, const int* in_sizes, int n_in,
                              void* d_out, int out_size, void* d_ws, size_t ws_size,
                              hipStream_t stream) {
    const float* X       = (const float*)d_in[0];   // 256*64
    const float* Y       = (const float*)d_in[1];   // 256*128
    const float* W       = (const float*)d_in[2];   // 128*64
    const float* b       = (const float*)d_in[3];   // 128
    const float* d_delta = (const float*)d_in[4];   // 1
    const float* d_gamma = (const float*)d_in[5];   // 1

    float* z_out    = (float*)d_out;                // Z_star: 256*128
    float* yhat_out = z_out + T_OBS * NY;           // Y_hat:  256*128
    float* ep_ws    = (float*)d_ws;                 // 256*128 scratch

    pred_kernel<<<T_OBS, 128, 0, stream>>>(X, Y, W, b, yhat_out, ep_ws);
    dro_kernel<<<T_OBS, 256, 0, stream>>>(ep_ws, yhat_out, z_out, d_delta, d_gamma);
}

// Round 7
// 228.511 us; speedup vs baseline: 1.5841x; 1.5841x over previous
//
#include <hip/hip_runtime.h>
#include <math.h>

#define T_OBS 256
#define NY 128
#define NITER 150

// ---- gfx9/CDNA DPP wave64 reduction: row_shr 1,2,4,8 + bcast15 + bcast31 ----
#define DPP_ROW_SHR1 0x111
#define DPP_ROW_SHR2 0x112
#define DPP_ROW_SHR4 0x114
#define DPP_ROW_SHR8 0x118
#define DPP_BCAST15  0x142
#define DPP_BCAST31  0x143

#define DPP_ADD_F32(x, ctrl) \
    (x) += __int_as_float(__builtin_amdgcn_update_dpp(0, __float_as_int(x), (ctrl), 0xf, 0xf, true))

// Interleaved dual wave-sum; returns uniform totals in a,b.
__device__ __forceinline__ void wave_sum2(float& a, float& b) {
    DPP_ADD_F32(a, DPP_ROW_SHR1); DPP_ADD_F32(b, DPP_ROW_SHR1);
    DPP_ADD_F32(a, DPP_ROW_SHR2); DPP_ADD_F32(b, DPP_ROW_SHR2);
    DPP_ADD_F32(a, DPP_ROW_SHR4); DPP_ADD_F32(b, DPP_ROW_SHR4);
    DPP_ADD_F32(a, DPP_ROW_SHR8); DPP_ADD_F32(b, DPP_ROW_SHR8);
    DPP_ADD_F32(a, DPP_BCAST15);  DPP_ADD_F32(b, DPP_BCAST15);
    DPP_ADD_F32(a, DPP_BCAST31);  DPP_ADD_F32(b, DPP_BCAST31);
    a = __int_as_float(__builtin_amdgcn_readlane(__float_as_int(a), 63));
    b = __int_as_float(__builtin_amdgcn_readlane(__float_as_int(b), 63));
}

__device__ __forceinline__ float rl(float x, int l) {
    return __int_as_float(__builtin_amdgcn_readlane(__float_as_int(x), l));
}

// ---------------- kernel 1: Y_hat = X @ W^T + b ; ep = Y - Y_hat ----------------
__global__ __launch_bounds__(128)
void pred_kernel(const float* __restrict__ X, const float* __restrict__ Y,
                 const float* __restrict__ W, const float* __restrict__ b,
                 float* __restrict__ yhat, float* __restrict__ ep) {
    __shared__ float xrow[64];
    const int t = blockIdx.x;
    const int j = threadIdx.x;
    if (j < 64) xrow[j] = X[t * 64 + j];
    __syncthreads();
    const float* wr = W + j * 64;
    float acc = 0.f;
#pragma unroll
    for (int x = 0; x < 64; ++x) acc = fmaf(xrow[x], wr[x], acc);
    const float yh = acc + b[j];
    yhat[t * NY + j] = yh;
    ep[t * NY + j] = Y[t * NY + j] - yh;
}

// ---------------- kernel 2: one DRO solve per block ----------------
// R1 structure exactly (readlane broadcasts on the VALU pipe, ONE barrier/iter).
// Projection: ungated thresholding fixed point S_{m+1} = {v > theta(S_m)}
// (reactivation allowed) — converges to the same unique KKT support as the
// act-gated Michelot + violator-restart, but with ONE reduction chain and ONE
// ballot per inner step and no outer attempt loop.
__global__ __launch_bounds__(256, 1)
void dro_kernel(const float* __restrict__ ep_g, const float* __restrict__ yhat_g,
                float* __restrict__ z_out,
                const float* __restrict__ d_delta, const float* __restrict__ d_gamma) {
    __shared__ float gzp[2][4][NY];              // cross-wave partials, dbuf
    __shared__ __align__(16) float red[2][8];    // cross-wave {S1,S2}, dbuf

    const int tid  = threadIdx.x;
    const int lane = tid & 63;
    const int wid  = tid >> 6;
    const int blk  = blockIdx.x;

    // row layout: thread tid holds ep[tid][0..127] (128 VGPRs)
    float4 rA[32];
    {
        const float4* eg4 = (const float4*)ep_g + tid * 32;
#pragma unroll
        for (int q = 0; q < 32; ++q) rA[q] = eg4[q];
    }

    // col layout: lane holds ep[tbase+tt][j0..j0+1] (128 VGPRs)
    const int j0    = lane << 1;
    const int tbase = wid << 6;
    float2 rB[64];
#pragma unroll
    for (int tt = 0; tt < 64; ++tt)
        rB[tt] = *(const float2*)(ep_g + (tbase + tt) * NY + j0);

    const float yh0 = yhat_g[blk * NY + j0];
    const float yh1 = yhat_g[blk * NY + j0 + 1];

    // z pair in registers (each wave holds a full redundant copy across lanes)
    float z0 = 1.0f / 128.0f, z1 = 1.0f / 128.0f;
    // warm-start support indicators (carried across iterations)
    float act0 = 1.f, act1 = 1.f;

    const float delta = d_delta[0];
    const float gamma = d_gamma[0];
    float c = 0.f, eta = 0.f, lam = 0.1f;
    int buf = 0;

    for (int k = 0; k < NITER; ++k) {
        const float lr = 0.05f * __builtin_amdgcn_rsqf(1.0f + (float)k);

        // ---- phase A: r_t = ep[t,:].z - c ; z broadcast via readlane ----
        float a0 = 0.f, a1 = 0.f, a2 = 0.f, a3 = 0.f;
#pragma unroll
        for (int q = 0; q < 32; ++q) {
            const float4 e = rA[q];
            const float za = rl(z0, 2 * q);
            const float zb = rl(z1, 2 * q);
            const float zc = rl(z0, 2 * q + 1);
            const float zd = rl(z1, 2 * q + 1);
            a0 = fmaf(e.x, za, a0);
            a1 = fmaf(e.y, zb, a1);
            a2 = fmaf(e.z, zc, a2);
            a3 = fmaf(e.w, zd, a3);
        }
        const float r  = (a0 + a1) + (a2 + a3) - c;
        const float q2 = r * r - eta;
        const float aa = -lam;
        const float st = (q2 > aa) ? 1.0f : ((q2 == aa) ? 0.5f : 0.0f);
        const float wv = st * r;

        // ---- S1/S2 reduction (independent of phase B; scheduler interleaves) ----
        float s1 = st, s2 = wv;
        wave_sum2(s1, s2);
        if (lane == 0) { red[buf][wid * 2] = s1; red[buf][wid * 2 + 1] = s2; }

        // ---- phase B: per-wave partial gz over own 64 rows; w via readlane ----
        float p0 = 0.f, p1 = 0.f, p2 = 0.f, p3 = 0.f;
#pragma unroll
        for (int tt = 0; tt < 64; tt += 2) {
            const float wa = rl(wv, tt);
            const float wb = rl(wv, tt + 1);
            const float2 ea = rB[tt];
            const float2 eb = rB[tt + 1];
            p0 = fmaf(wa, ea.x, p0);
            p1 = fmaf(wa, ea.y, p1);
            p2 = fmaf(wb, eb.x, p2);
            p3 = fmaf(wb, eb.y, p3);
        }
        *(float2*)&gzp[buf][wid][j0] = make_float2(p0 + p2, p1 + p3);

        __syncthreads();   // the ONE barrier: gzp[buf] + red[buf] visible

        // ---- all waves redundantly: scalar updates + z step + projection ----
        const float4 rd0 = *(const float4*)&red[buf][0];
        const float4 rd1 = *(const float4*)&red[buf][4];
        const float S1 = (rd0.x + rd0.z) + (rd1.x + rd1.z);
        const float S2 = (rd0.y + rd0.w) + (rd1.y + rd1.w);
        c   -= lr * (-(2.0f / 256.0f) * S2);
        eta -= lr * (1.0f - S1 * (1.0f / 256.0f));
        lam  = fmaxf(lam - lr * (delta - 1.0f + S1 * (1.0f / 256.0f)), 0.0f);

        const float2 g0v = *(const float2*)&gzp[buf][0][j0];
        const float2 g1v = *(const float2*)&gzp[buf][1][j0];
        const float2 g2v = *(const float2*)&gzp[buf][2][j0];
        const float2 g3v = *(const float2*)&gzp[buf][3][j0];
        const float g0 = (g0v.x + g1v.x) + (g2v.x + g3v.x);
        const float g1 = (g0v.y + g1v.y) + (g2v.y + g3v.y);
        const float v0 = z0 - lr * ((2.0f / 256.0f) * g0 - gamma * yh0);
        const float v1 = z1 - lr * ((2.0f / 256.0f) * g1 - gamma * yh1);

        // ---- simplex projection: ungated thresholding fixed point.
        // theta from current support S; new S = {v > theta} (reactivation
        // allowed). Stable S == exact KKT support; summation order over the
        // converged S is identical to the gated version -> same theta bits.
        float theta = 0.f;
        for (int m = 0; m < 64; ++m) {
            float s  = act0 * v0 + act1 * v1;
            float cc = act0 + act1;
            wave_sum2(s, cc);
            theta = (s - 1.0f) * __builtin_amdgcn_rcpf(cc);
            const float n0 = (v0 > theta) ? 1.0f : 0.0f;
            const float n1 = (v1 > theta) ? 1.0f : 0.0f;
            const bool changed = (n0 != act0) || (n1 != act1);
            act0 = n0; act1 = n1;
            if (!__any(changed)) break;   // stable support == exact
        }
        z0 = fmaxf(v0 - theta, 0.f);
        z1 = fmaxf(v1 - theta, 0.f);

        buf ^= 1;
    }

    if (wid == 0) *(float2*)&z_out[blk * NY + j0] = make_float2(z0, z1);
}

extern "C" void kernel_launch(void* const* d_in, const int* in_sizes, int n_in,
                              void* d_out, int out_size, void* d_ws, size_t ws_size,
                              hipStream_t stream) {
    const float* X       = (const float*)d_in[0];   // 256*64
    const float* Y       = (const float*)d_in[1];   // 256*128
    const float* W       = (const float*)d_in[2];   // 128*64
    const float* b       = (const float*)d_in[3];   // 128
    const float* d_delta = (const float*)d_in[4];   // 1
    const float* d_gamma = (const float*)d_in[5];   // 1

    float* z_out    = (float*)d_out;                // Z_star: 256*128
    float* yhat_out = z_out + T_OBS * NY;           // Y_hat:  256*128
    float* ep_ws    = (float*)d_ws;                 // 256*128 scratch

    pred_kernel<<<T_OBS, 128, 0, stream>>>(X, Y, W, b, yhat_out, ep_ws);
    dro_kernel<<<T_OBS, 256, 0, stream>>>(ep_ws, yhat_out, z_out, d_delta, d_gamma);
}